// Round 1
// baseline (266.565 us; speedup 1.0000x reference)
//
#include <hip/hip_runtime.h>
#include <hip/hip_bf16.h>

#define NPTS 262144
#define NC 64
#define NK 27

__device__ __forceinline__ unsigned bfr(float x) {
    unsigned u = __float_as_uint(x);
    return (u + 0x7fffu + ((u >> 16) & 1u)) >> 16;   // round-to-nearest-even bf16 bits
}
__device__ __forceinline__ float bflo(unsigned u) { return __uint_as_float(u << 16); }
__device__ __forceinline__ float bfhi(unsigned u) { return __uint_as_float(u & 0xffff0000u); }

// Kernel A: bx[r][c] = sum_j feat[r][j] * W[j][c] + b1[c], stored bf16.
// One thread per row; W staged in LDS, read via wave-uniform (broadcast) b128 loads.
__global__ __launch_bounds__(256) void gemm_bias(const float* __restrict__ feat,
                                                 const float* __restrict__ W,
                                                 const float* __restrict__ b1,
                                                 ushort* __restrict__ bx) {
    __shared__ float Ws[NC * NC];
    int t = threadIdx.x;
#pragma unroll
    for (int i = 0; i < 4; ++i)
        ((float4*)Ws)[t + i * 256] = ((const float4*)W)[t + i * 256];
    __syncthreads();

    long row = (long)blockIdx.x * 256 + t;
    const float4* frow = (const float4*)(feat + row * NC);

    float acc[NC];
#pragma unroll
    for (int cq = 0; cq < 16; ++cq) {
        float4 b = ((const float4*)b1)[cq];
        acc[cq * 4 + 0] = b.x; acc[cq * 4 + 1] = b.y;
        acc[cq * 4 + 2] = b.z; acc[cq * 4 + 3] = b.w;
    }

    for (int jq = 0; jq < 16; ++jq) {
        float4 f = frow[jq];
#pragma unroll
        for (int cq = 0; cq < 16; ++cq) {
            float4 w0 = ((const float4*)(Ws + (jq * 4 + 0) * NC))[cq];
            float4 w1 = ((const float4*)(Ws + (jq * 4 + 1) * NC))[cq];
            float4 w2 = ((const float4*)(Ws + (jq * 4 + 2) * NC))[cq];
            float4 w3 = ((const float4*)(Ws + (jq * 4 + 3) * NC))[cq];
            acc[cq * 4 + 0] += f.x * w0.x; acc[cq * 4 + 0] += f.y * w1.x;
            acc[cq * 4 + 0] += f.z * w2.x; acc[cq * 4 + 0] += f.w * w3.x;
            acc[cq * 4 + 1] += f.x * w0.y; acc[cq * 4 + 1] += f.y * w1.y;
            acc[cq * 4 + 1] += f.z * w2.y; acc[cq * 4 + 1] += f.w * w3.y;
            acc[cq * 4 + 2] += f.x * w0.z; acc[cq * 4 + 2] += f.y * w1.z;
            acc[cq * 4 + 2] += f.z * w2.z; acc[cq * 4 + 2] += f.w * w3.z;
            acc[cq * 4 + 3] += f.x * w0.w; acc[cq * 4 + 3] += f.y * w1.w;
            acc[cq * 4 + 3] += f.z * w2.w; acc[cq * 4 + 3] += f.w * w3.w;
        }
    }

    uint4* orow = (uint4*)(bx + row * NC);
#pragma unroll
    for (int q = 0; q < 8; ++q) {
        uint4 v;
        v.x = bfr(acc[q * 8 + 0]) | (bfr(acc[q * 8 + 1]) << 16);
        v.y = bfr(acc[q * 8 + 2]) | (bfr(acc[q * 8 + 3]) << 16);
        v.z = bfr(acc[q * 8 + 4]) | (bfr(acc[q * 8 + 5]) << 16);
        v.w = bfr(acc[q * 8 + 6]) | (bfr(acc[q * 8 + 7]) << 16);
        orow[q] = v;
    }
}

// Kernel B: out[r][c] = feat[r][c] + b2[c] + sum_{k valid} bx[nb[r][k]][c] * dw[k][c]
// 8 lanes per row (8 channels each), 32 rows per block, chunked XCD swizzle.
__global__ __launch_bounds__(256) void dwconv(const float* __restrict__ feat,
                                              const int* __restrict__ nb,
                                              const float* __restrict__ b2,
                                              const float* __restrict__ dw,
                                              const ushort* __restrict__ bx,
                                              float* __restrict__ out) {
    __shared__ float dwS[NK * NC];
    __shared__ float b2S[NC];
    int t = threadIdx.x;
    for (int i = t; i < NK * NC; i += 256) dwS[i] = dw[i];
    if (t < NC) b2S[t] = b2[t];
    __syncthreads();

    // bijective chunked XCD swizzle (gridDim.x = 8192, divisible by 8)
    int b = blockIdx.x;
    int chunk = gridDim.x >> 3;
    int sb = (b & 7) * chunk + (b >> 3);

    long row = (long)sb * 32 + (t >> 3);
    int c0 = (t & 7) * 8;

    const float* fp = feat + row * NC + c0;
    float4 fa = *(const float4*)fp;
    float4 fb = *(const float4*)(fp + 4);
    float acc0 = fa.x + b2S[c0 + 0];
    float acc1 = fa.y + b2S[c0 + 1];
    float acc2 = fa.z + b2S[c0 + 2];
    float acc3 = fa.w + b2S[c0 + 3];
    float acc4 = fb.x + b2S[c0 + 4];
    float acc5 = fb.y + b2S[c0 + 5];
    float acc6 = fb.z + b2S[c0 + 6];
    float acc7 = fb.w + b2S[c0 + 7];

    const int* nrow = nb + row * NK;
#pragma unroll
    for (int k = 0; k < NK; ++k) {
        int idx = nrow[k];
        if (idx >= 0) {
            uint4 v = *(const uint4*)(bx + (long)idx * NC + c0);
            float4 w0 = *(const float4*)(dwS + k * NC + c0);
            float4 w1 = *(const float4*)(dwS + k * NC + c0 + 4);
            acc0 += bflo(v.x) * w0.x;
            acc1 += bfhi(v.x) * w0.y;
            acc2 += bflo(v.y) * w0.z;
            acc3 += bfhi(v.y) * w0.w;
            acc4 += bflo(v.z) * w1.x;
            acc5 += bfhi(v.z) * w1.y;
            acc6 += bflo(v.w) * w1.z;
            acc7 += bfhi(v.w) * w1.w;
        }
    }

    float* op = out + row * NC + c0;
    *(float4*)op = make_float4(acc0, acc1, acc2, acc3);
    *(float4*)(op + 4) = make_float4(acc4, acc5, acc6, acc7);
}

extern "C" void kernel_launch(void* const* d_in, const int* in_sizes, int n_in,
                              void* d_out, int out_size, void* d_ws, size_t ws_size,
                              hipStream_t stream) {
    const float* feat = (const float*)d_in[0];
    const int*   nb   = (const int*)d_in[1];
    const float* W    = (const float*)d_in[2];
    const float* b1   = (const float*)d_in[3];
    const float* b2   = (const float*)d_in[4];
    const float* dw   = (const float*)d_in[5];
    float* out = (float*)d_out;
    ushort* bx = (ushort*)d_ws;   // N*C bf16 = 33.5 MB scratch

    gemm_bias<<<NPTS / 256, 256, 0, stream>>>(feat, W, b1, bx);
    dwconv<<<NPTS / 32, 256, 0, stream>>>(feat, nb, b2, dw, bx, out);
}

// Round 2
// 211.917 us; speedup vs baseline: 1.2579x; 1.2579x over previous
//
#include <hip/hip_runtime.h>
#include <hip/hip_bf16.h>

#define NPTS 262144
#define NC 64
#define NK 27

typedef __attribute__((ext_vector_type(8))) short bf16x8;
typedef __attribute__((ext_vector_type(4))) float f32x4;

__device__ __forceinline__ unsigned bfr(float x) {
    unsigned u = __float_as_uint(x);
    return (u + 0x7fffu + ((u >> 16) & 1u)) >> 16;   // RNE bf16 bits
}
__device__ __forceinline__ float bflo(unsigned u) { return __uint_as_float(u << 16); }
__device__ __forceinline__ float bfhi(unsigned u) { return __uint_as_float(u & 0xffff0000u); }

__device__ __forceinline__ unsigned cvtpk(float lo, float hi) {
    unsigned r;
    asm("v_cvt_pk_bf16_f32 %0, %1, %2" : "=v"(r) : "v"(lo), "v"(hi));
    return r;
}

union BF { unsigned u[4]; bf16x8 v; };

// Kernel A (MFMA): bx[r][c] = bf16(sum_j feat[r][j]*W[j][c] + b1[c]).
// 4 waves/block, each wave owns 16-row tiles (grid-stride). W fragments built
// once per wave from LDS; A converted fp32->bf16 via v_cvt_pk_bf16_f32.
// mfma_f32_16x16x32_bf16: A lane: row=l&15, k=(l>>4)*8+j ; B lane: col=l&15,
// k=(l>>4)*8+j ; C/D lane: col=l&15, row=(l>>4)*4+i  (guide §3, m89-verified).
__global__ __launch_bounds__(256) void gemm_mfma(const float* __restrict__ feat,
                                                 const float* __restrict__ W,
                                                 const float* __restrict__ b1,
                                                 ushort* __restrict__ bx) {
    __shared__ float Ws[NC * NC];
    __shared__ float b1S[NC];
    int t = threadIdx.x;
#pragma unroll
    for (int i = 0; i < 4; ++i)
        ((float4*)Ws)[t + i * 256] = ((const float4*)W)[t + i * 256];
    if (t < NC) b1S[t] = b1[t];
    __syncthreads();

    int lane = t & 63;
    int col = lane & 15;
    int kg = lane >> 4;
    int wid = blockIdx.x * 4 + (t >> 6);      // 4096 waves total
    const int NWAVES = 1024 * 4;
    const int NTILES = NPTS / 16;             // 16384

    // Build B fragments (2 k-steps x 4 col-tiles), held in regs for all tiles.
    BF Bf[2][4];
#pragma unroll
    for (int ks = 0; ks < 2; ++ks)
#pragma unroll
        for (int ct = 0; ct < 4; ++ct)
#pragma unroll
            for (int r = 0; r < 4; ++r) {
                float lo = Ws[(ks * 32 + kg * 8 + 2 * r) * NC + ct * 16 + col];
                float hi = Ws[(ks * 32 + kg * 8 + 2 * r + 1) * NC + ct * 16 + col];
                Bf[ks][ct].u[r] = cvtpk(lo, hi);
            }
    float bias[4];
#pragma unroll
    for (int ct = 0; ct < 4; ++ct) bias[ct] = b1S[ct * 16 + col];

    for (int tile = wid; tile < NTILES; tile += NWAVES) {
        long r0 = (long)tile * 16;
        const float* ap = feat + (r0 + col) * NC + kg * 8;
        float4 a0 = *(const float4*)(ap);
        float4 a1 = *(const float4*)(ap + 4);
        float4 a2 = *(const float4*)(ap + 32);
        float4 a3 = *(const float4*)(ap + 36);
        BF A0, A1;
        A0.u[0] = cvtpk(a0.x, a0.y); A0.u[1] = cvtpk(a0.z, a0.w);
        A0.u[2] = cvtpk(a1.x, a1.y); A0.u[3] = cvtpk(a1.z, a1.w);
        A1.u[0] = cvtpk(a2.x, a2.y); A1.u[1] = cvtpk(a2.z, a2.w);
        A1.u[2] = cvtpk(a3.x, a3.y); A1.u[3] = cvtpk(a3.z, a3.w);

        f32x4 acc[4];
#pragma unroll
        for (int ct = 0; ct < 4; ++ct) {
            acc[ct] = (f32x4){bias[ct], bias[ct], bias[ct], bias[ct]};
            acc[ct] = __builtin_amdgcn_mfma_f32_16x16x32_bf16(A0.v, Bf[0][ct].v, acc[ct], 0, 0, 0);
            acc[ct] = __builtin_amdgcn_mfma_f32_16x16x32_bf16(A1.v, Bf[1][ct].v, acc[ct], 0, 0, 0);
        }

        ushort* op = bx + (r0 + kg * 4) * NC + col;
#pragma unroll
        for (int i = 0; i < 4; ++i)
#pragma unroll
            for (int ct = 0; ct < 4; ++ct)
                op[i * NC + ct * 16] = (ushort)bfr(acc[ct][i]);
    }
}

// Kernel B: out[r][c] = feat[r][c] + b2[c] + sum_k dw[k][c]*bx[nb[r][k]][c]
// 8 lanes/row, 32 rows/block. All 27 nb indices hoisted into regs (27 loads in
// flight); wave-uniform __any() skip; per-lane predication via cndmask on the
// gathered words (no divergent branch around the load).
__global__ __launch_bounds__(256) void dwconv(const float* __restrict__ feat,
                                              const int* __restrict__ nb,
                                              const float* __restrict__ b2,
                                              const float* __restrict__ dw,
                                              const ushort* __restrict__ bx,
                                              float* __restrict__ out) {
    __shared__ float dwS[NK * NC];
    __shared__ float b2S[NC];
    int t = threadIdx.x;
    for (int i = t; i < NK * NC; i += 256) dwS[i] = dw[i];
    if (t < NC) b2S[t] = b2[t];
    __syncthreads();

    // bijective chunked XCD swizzle (gridDim.x = 8192, %8 == 0)
    int b = blockIdx.x;
    int chunk = gridDim.x >> 3;
    int sb = (b & 7) * chunk + (b >> 3);

    long row = (long)sb * 32 + (t >> 3);
    int c0 = (t & 7) * 8;

    const int* nrow = nb + row * NK;
    int idx[NK];
#pragma unroll
    for (int k = 0; k < NK; ++k) idx[k] = nrow[k];

    const float* fp = feat + row * NC + c0;
    float4 fa = *(const float4*)fp;
    float4 fb = *(const float4*)(fp + 4);

    float acc0 = 0.f, acc1 = 0.f, acc2 = 0.f, acc3 = 0.f;
    float acc4 = 0.f, acc5 = 0.f, acc6 = 0.f, acc7 = 0.f;

#pragma unroll
    for (int k = 0; k < NK; ++k) {
        int id = idx[k];
        bool v = id >= 0;
        if (__any(v)) {
            int ids = v ? id : 0;
            uint4 g = *(const uint4*)(bx + (size_t)ids * NC + c0);
            if (!v) { g.x = 0u; g.y = 0u; g.z = 0u; g.w = 0u; }
            float4 w0 = *(const float4*)(dwS + k * NC + c0);
            float4 w1 = *(const float4*)(dwS + k * NC + c0 + 4);
            acc0 += bflo(g.x) * w0.x;
            acc1 += bfhi(g.x) * w0.y;
            acc2 += bflo(g.y) * w0.z;
            acc3 += bfhi(g.y) * w0.w;
            acc4 += bflo(g.z) * w1.x;
            acc5 += bfhi(g.z) * w1.y;
            acc6 += bflo(g.w) * w1.z;
            acc7 += bfhi(g.w) * w1.w;
        }
    }

    float* op = out + row * NC + c0;
    *(float4*)op = make_float4(acc0 + fa.x + b2S[c0 + 0],
                               acc1 + fa.y + b2S[c0 + 1],
                               acc2 + fa.z + b2S[c0 + 2],
                               acc3 + fa.w + b2S[c0 + 3]);
    *(float4*)(op + 4) = make_float4(acc4 + fb.x + b2S[c0 + 4],
                                     acc5 + fb.y + b2S[c0 + 5],
                                     acc6 + fb.z + b2S[c0 + 6],
                                     acc7 + fb.w + b2S[c0 + 7]);
}

extern "C" void kernel_launch(void* const* d_in, const int* in_sizes, int n_in,
                              void* d_out, int out_size, void* d_ws, size_t ws_size,
                              hipStream_t stream) {
    const float* feat = (const float*)d_in[0];
    const int*   nb   = (const int*)d_in[1];
    const float* W    = (const float*)d_in[2];
    const float* b1   = (const float*)d_in[3];
    const float* b2   = (const float*)d_in[4];
    const float* dw   = (const float*)d_in[5];
    float* out = (float*)d_out;
    ushort* bx = (ushort*)d_ws;   // N*C bf16 = 33.5 MB scratch

    gemm_mfma<<<1024, 256, 0, stream>>>(feat, W, b1, bx);
    dwconv<<<NPTS / 32, 256, 0, stream>>>(feat, nb, b2, dw, bx, out);
}